// Round 21
// baseline (113.307 us; speedup 1.0000x reference)
//
#include <hip/hip_runtime.h>
#include <cstdint>
#include <cstddef>

#define S_LEN 2048
#define NH 16
#define HD 64
#define DM 1024
#define WIN 1024

typedef unsigned short u16;
typedef __attribute__((ext_vector_type(8))) short bf16x8;
typedef __attribute__((ext_vector_type(4))) short bf16x4;
typedef __attribute__((ext_vector_type(4))) float f32x4;
typedef __attribute__((ext_vector_type(4))) u16 u16x4;
typedef __attribute__((ext_vector_type(2))) uint32_t u32x2;
typedef __attribute__((ext_vector_type(4))) uint32_t u32x4;

__device__ inline u16 f2b(float f) {
  union { float f; uint32_t u; } x; x.f = f;
  uint32_t r = x.u + 0x7FFFu + ((x.u >> 16) & 1u);
  return (u16)(r >> 16);
}

__device__ inline uint32_t cvt_pk_bf16(float a, float b) {
  uint32_t r;
  asm("v_cvt_pk_bf16_f32 %0, %1, %2" : "=v"(r) : "v"(a), "v"(b));
  return r;
}

__device__ inline void gload16(const void* g, void* l) {
  __builtin_amdgcn_global_load_lds((const __attribute__((address_space(1))) void*)g,
                                   (__attribute__((address_space(3))) void*)l, 16, 0, 0);
}

// ---------------- fused f32 -> bf16 conversion (x + 4 weights, 1 dispatch) --
__global__ __launch_bounds__(256)
void cvt_all(const float* __restrict__ x,
             const float* __restrict__ wq, const float* __restrict__ wk,
             const float* __restrict__ wv, const float* __restrict__ wo,
             u16* __restrict__ xb, u16* __restrict__ wqkvb, u16* __restrict__ wob) {
  size_t i = ((size_t)blockIdx.x * 256 + threadIdx.x) * 4;
  const float* src; u16* dst;
  if (i < 4194304) {                      // x (blocks 0..4095, uniform)
    src = x + i; dst = xb + i;
  } else {
    size_t j = i - 4194304;
    int w = (int)(j >> 20);
    size_t off = j & 1048575;
    switch (w) {
      case 0:  src = wq + off; dst = wqkvb + off; break;
      case 1:  src = wk + off; dst = wqkvb + 1048576 + off; break;
      case 2:  src = wv + off; dst = wqkvb + 2097152 + off; break;
      default: src = wo + off; dst = wob + off; break;
    }
  }
  f32x4 v = *(const f32x4*)src;
  u16x4 o;
  o[0] = f2b(v[0]); o[1] = f2b(v[1]); o[2] = f2b(v[2]); o[3] = f2b(v[3]);
  *(u16x4*)dst = o;
}

// ---------------- bf16 NT GEMM: BK=64, XOR-swizzled LDS, XCD-stripe ---------
// A:[M][K], B:[N][K] bf16 row-major. 128^2 tile, 4 waves x 64x64, BK=64.
// EPI 0: f32 -> outF[row*N+col], bias b0[col]
// EPI 1: QK epilogue: which=col>>10 in {0,1}, bias b0/b1, outQ row layout
// EPI 2: V^T epilogue: C[vd][bs] = V^T; write Vt[(b*NH+h)][d][s] coalesced in s,
//        bias b0[row] (per v-dim)
template<int EPI>
__global__ __launch_bounds__(256, 4)
void gemm_nt(const u16* __restrict__ A, const u16* __restrict__ B,
             const float* __restrict__ b0, const float* __restrict__ b1,
             const float* __restrict__ b2,
             float* __restrict__ outF, u16* __restrict__ outQ,
             int M, int N, int K) {
  __shared__ u16 As[128 * 64];   // 16KB
  __shared__ u16 Bs[128 * 64];   // 16KB
  const int t = threadIdx.x;
  const int lane = t & 63, wid = t >> 6;
  const int l15 = lane & 15, l4 = lane >> 4;
  const int x = l15 & 7;
  const int wr = wid >> 1, wc = wid & 1;         // 2x2 wave grid, 64x64/wave
  const int bmB = M >> 7, bnB = N >> 7;
  const int stripe = bmB >> 3;
  const int per = stripe * bnB;                  // jobs per XCD
  const int job = (blockIdx.x & 7) * per + (blockIdx.x >> 3);
  const int r_ = job % per;
  const int bm = ((job / per) * stripe + r_ / bnB) << 7;
  const int bn = (r_ % bnB) << 7;
  const int srow0 = t >> 3;
  const int colx = ((t * 16) & 127) ^ (((t >> 3) & 7) << 4);
  const char* Ap = (const char*)A + ((size_t)(bm + srow0) * K) * 2 + colx;
  const char* Bp = (const char*)B + ((size_t)(bn + srow0) * K) * 2 + colx;
  const size_t sstr = (size_t)32 * K * 2;        // +32 rows per shot
  char* Asd = (char*)As + t * 16;
  char* Bsd = (char*)Bs + t * 16;
  f32x4 acc[4][4];
#pragma unroll
  for (int i = 0; i < 4; i++)
#pragma unroll
    for (int j = 0; j < 4; j++) acc[i][j] = (f32x4){0.f, 0.f, 0.f, 0.f};

  for (int kb = 0; kb < K; kb += 64) {
    __syncthreads();
#pragma unroll
    for (int shot = 0; shot < 4; shot++) {
      gload16(Ap + (size_t)kb * 2 + shot * sstr, Asd + shot * 4096);
      gload16(Bp + (size_t)kb * 2 + shot * sstr, Bsd + shot * 4096);
    }
    __syncthreads();
#pragma unroll
    for (int ks2 = 0; ks2 < 2; ks2++) {
      bf16x8 af[4], bq[4];
#pragma unroll
      for (int mi = 0; mi < 4; mi++)
        af[mi] = *(bf16x8*)&As[(wr * 64 + mi * 16 + l15) * 64 +
                               (((ks2 * 4 + l4) ^ x) << 3)];
#pragma unroll
      for (int ni = 0; ni < 4; ni++)
        bq[ni] = *(bf16x8*)&Bs[(wc * 64 + ni * 16 + l15) * 64 +
                               (((ks2 * 4 + l4) ^ x) << 3)];
#pragma unroll
      for (int mi = 0; mi < 4; mi++)
#pragma unroll
        for (int ni = 0; ni < 4; ni++)
          acc[mi][ni] = __builtin_amdgcn_mfma_f32_16x16x32_bf16(af[mi], bq[ni], acc[mi][ni], 0, 0, 0);
    }
  }

  const int cb = bn >> 10;
  const float* bp = (EPI == 1) ? (cb == 0 ? b0 : b1) : b0;
#pragma unroll
  for (int mi = 0; mi < 4; mi++) {
#pragma unroll
    for (int ni = 0; ni < 4; ni++) {
#pragma unroll
      for (int r = 0; r < 4; r++) {
        int row = bm + wr * 64 + mi * 16 + l4 * 4 + r;
        int col = bn + wc * 64 + ni * 16 + l15;
        if (EPI == 0) {
          float v = acc[mi][ni][r] + bp[col];
          outF[(size_t)row * N + col] = v;
        } else if (EPI == 1) {
          float v = acc[mi][ni][r] + bp[col & (DM - 1)];
          int b = row >> 11, s = row & (S_LEN - 1);
          int which = col >> 10, cw = col & (DM - 1);
          int h = cw >> 6, d = cw & (HD - 1);
          outQ[(size_t)which * 4194304 +
               (((size_t)(b * NH + h)) * S_LEN + s) * HD + d] = f2b(v);
        } else {
          float v = acc[mi][ni][r] + bp[row];       // bias per v-dim (row)
          int b = col >> 11, s = col & (S_LEN - 1); // col = (b, s)
          int h = row >> 6, d = row & (HD - 1);     // row = (h, d)
          outQ[(((size_t)(b * NH + h)) * HD + d) * S_LEN + s] = f2b(v);
        }
      }
    }
  }
}

// ---------------- attention: R16-proven (fixed-base softmax, dbuf LDS) ------
__device__ __forceinline__ void stage_tiles(const char* __restrict__ Kg,
                                            const char* __restrict__ Vg,
                                            u16* __restrict__ Kl, u16* __restrict__ Vl,
                                            int t) {
#pragma unroll
  for (int shot = 0; shot < 2; shot++) {
    int o = shot * 4096 + t * 16;
    int sw = ((o >> 7) & 7) << 4;
    gload16(Kg + (o ^ sw), (char*)Kl + o);
    gload16(Vg + (size_t)(o >> 7) * 4096 + ((o & 127) ^ sw), (char*)Vl + o);
  }
}

__device__ __forceinline__ void process_tile16(
    int kb, const u16* __restrict__ Kl, const u16* __restrict__ Vl,
    const bf16x8 qf[2], const float c16[16],
    int qw, int l15, int hi, float slope2, float qks,
    float& lsum, f32x4 O[4]) {
  const int x = l15 & 7;
  f32x4 st[4];
#pragma unroll
  for (int f = 0; f < 4; f++) st[f] = (f32x4){0.f, 0.f, 0.f, 0.f};
#pragma unroll
  for (int ks = 0; ks < 2; ks++)
#pragma unroll
    for (int f = 0; f < 4; f++) {
      bf16x8 kf = *(const bf16x8*)&Kl[(16 * f + l15) * 64 + (((4 * ks + hi) ^ x) << 3)];
      st[f] = __builtin_amdgcn_mfma_f32_16x16x32_bf16(kf, qf[ks], st[f], 0, 0, 0);
    }

  const int dkb = kb + 4 * hi - (qw + l15);
  const float base = slope2 * (float)dkb - 8.f;   // fixed base M0=8 folded in
  const bool interior = (kb + 63 <= qw) && (kb - (qw + 15) > -WIN);
  float p[16];
  if (interior) {
#pragma unroll
    for (int f = 0; f < 4; f++)
#pragma unroll
      for (int r = 0; r < 4; r++)
        p[4 * f + r] = fmaf(st[f][r], qks, base + c16[4 * f + r]);
  } else {
#pragma unroll
    for (int f = 0; f < 4; f++)
#pragma unroll
      for (int r = 0; r < 4; r++) {
        int dk = dkb + 16 * f + r;
        float s = fmaf(st[f][r], qks, base + c16[4 * f + r]);
        p[4 * f + r] = (dk > 0 || dk <= -WIN) ? -3e38f : s;
      }
  }

#pragma unroll
  for (int r = 0; r < 16; r++) p[r] = exp2f(p[r]);
  float a8[8];
#pragma unroll
  for (int r = 0; r < 8; r++) a8[r] = p[r] + p[r + 8];
#pragma unroll
  for (int r = 0; r < 4; r++) a8[r] += a8[r + 4];
  lsum += (a8[0] + a8[1]) + (a8[2] + a8[3]);

  bf16x8 pb[2];
#pragma unroll
  for (int kc = 0; kc < 2; kc++) {
    u32x4 w4;
    w4[0] = cvt_pk_bf16(p[8 * kc + 0], p[8 * kc + 1]);
    w4[1] = cvt_pk_bf16(p[8 * kc + 2], p[8 * kc + 3]);
    w4[2] = cvt_pk_bf16(p[8 * kc + 4], p[8 * kc + 5]);
    w4[3] = cvt_pk_bf16(p[8 * kc + 6], p[8 * kc + 7]);
    pb[kc] = __builtin_bit_cast(bf16x8, w4);
  }

#pragma unroll
  for (int d = 0; d < 4; d++) {
#pragma unroll
    for (int kc = 0; kc < 2; kc++) {
      const int row = (16 * d + l15) * 64;
      bf16x4 a = *(const bf16x4*)&Vl[row + (((4 * kc + (hi >> 1)) ^ x) << 3) + 4 * (hi & 1)];
      bf16x4 bql = *(const bf16x4*)&Vl[row + (((4 * kc + 2 + (hi >> 1)) ^ x) << 3) + 4 * (hi & 1)];
      bf16x8 vf;
      vf[0] = a[0]; vf[1] = a[1]; vf[2] = a[2]; vf[3] = a[3];
      vf[4] = bql[0]; vf[5] = bql[1]; vf[6] = bql[2]; vf[7] = bql[3];
      O[d] = __builtin_amdgcn_mfma_f32_16x16x32_bf16(vf, pb[kc], O[d], 0, 0, 0);
    }
  }
}

__global__ __launch_bounds__(256, 4)
void attn_kernel(const u16* __restrict__ Q, const u16* __restrict__ Kg,
                 const u16* __restrict__ Vt, u16* __restrict__ attn) {
  __shared__ __align__(16) u16 Klds[2][4096];
  __shared__ __align__(16) u16 Vlds[2][4096];
  const int bid = blockIdx.x;
  const int job = (bid & 7) * 128 + (bid >> 3);  // XCD swizzle (1024 % 8 == 0)
  const int bh = job >> 5;
  const int qb = ((31 - (job & 31)) + (bh << 3)) & 31;  // per-CU balance rotation
  const int b = bh >> 4, h = bh & 15;
  const int tid = threadIdx.x;
  const int wid = tid >> 6, lane = tid & 63;
  const int l15 = lane & 15, hi = lane >> 4;
  const int q0 = qb << 6;
  const int qw = q0 + 16 * wid;
  const u16* Qp = Q + (size_t)bh * (S_LEN * HD);
  const char* Kbase = (const char*)(Kg + (size_t)bh * (S_LEN * HD));
  const char* Vbase = (const char*)(Vt + (size_t)bh * (HD * S_LEN));

  bf16x8 qf[2];
#pragma unroll
  for (int ks = 0; ks < 2; ks++)
    qf[ks] = *(const bf16x8*)(Qp + (size_t)(qw + l15) * HD + 32 * ks + 8 * hi);

  const float slope2 = exp2f(-0.5f * (float)(h + 1)) * 1.44269504f;
  const float qks = 0.125f * 1.44269504f;
  float c16[16];
#pragma unroll
  for (int f = 0; f < 4; f++)
#pragma unroll
    for (int r = 0; r < 4; r++) c16[4 * f + r] = slope2 * (float)(16 * f + r);

  float lsum = 0.f;
  f32x4 O[4];
#pragma unroll
  for (int d = 0; d < 4; d++) O[d] = (f32x4){0.f, 0.f, 0.f, 0.f};

  int lo_u = q0 - (WIN - 1); if (lo_u < 0) lo_u = 0; lo_u &= ~63;
  const int hi_u = q0;
  int lo_w = qw - (WIN - 1); if (lo_w < 0) lo_w = 0; lo_w &= ~63;
  const int last_w = (qw + 15) & ~63;

  stage_tiles(Kbase + (size_t)lo_u * 128, Vbase + (size_t)lo_u * 2,
              Klds[0], Vlds[0], tid);
  int cur = 0;
  for (int kb = lo_u; kb <= hi_u; kb += 64) {
    __syncthreads();   // tile kb resident; prior reads of buf[cur^1] done
    if (kb + 64 <= hi_u)
      stage_tiles(Kbase + (size_t)(kb + 64) * 128, Vbase + (size_t)(kb + 64) * 2,
                  Klds[cur ^ 1], Vlds[cur ^ 1], tid);
    if (kb >= lo_w && kb <= last_w)    // wave-uniform branch
      process_tile16(kb, Klds[cur], Vlds[cur], qf, c16,
                     qw, l15, hi, slope2, qks, lsum, O);
    cur ^= 1;
  }

  // deferred cross-lane lsum reduce (row = lanes {l15, l15+16, l15+32, l15+48})
  lsum += __shfl_xor(lsum, 16, 64);
  lsum += __shfl_xor(lsum, 32, 64);

  const float invl = 1.f / lsum;
  u16* op = attn + ((size_t)(b * S_LEN) + qw + l15) * DM + h * HD + 4 * hi;
#pragma unroll
  for (int d = 0; d < 4; d++) {
    u32x2 w;
    w[0] = cvt_pk_bf16(O[d][0] * invl, O[d][1] * invl);
    w[1] = cvt_pk_bf16(O[d][2] * invl, O[d][3] * invl);
    *(u32x2*)(op + d * 16) = w;
  }
}

// ---------------- launch ----------------
extern "C" void kernel_launch(void* const* d_in, const int* in_sizes, int n_in,
                              void* d_out, int out_size, void* d_ws, size_t ws_size,
                              hipStream_t stream) {
  const float* x  = (const float*)d_in[0];
  const float* wq = (const float*)d_in[1];
  const float* bq = (const float*)d_in[2];
  const float* wk = (const float*)d_in[3];
  const float* bk = (const float*)d_in[4];
  const float* wv = (const float*)d_in[5];
  const float* bv = (const float*)d_in[6];
  const float* wo = (const float*)d_in[7];
  const float* bo = (const float*)d_in[8];

  char* ws = (char*)d_ws;
  u16* xb    = (u16*)(ws);                  // 8 MB  [4096][1024]
  u16* wqkvb = (u16*)(ws + 8388608);        // 6 MB  [3072][1024]
  u16* wob   = (u16*)(ws + 14680064);       // 2 MB  [1024][1024]
  u16* QKVb  = (u16*)(ws + 16777216);       // 16 MB used: Q|K row layout [bh][s][64]
  u16* Vtb   = (u16*)(ws + 41943040);       // 8 MB  [BH][64][S] (V^T direct)
  u16* Ab    = (u16*)(ws + 50331648);       // 8 MB  [B*S][1024]
  u16* wvb   = wqkvb + 2097152;

  const int M = 4096;

  cvt_all<<<dim3(8192), dim3(256), 0, stream>>>(x, wq, wk, wv, wo,
                                                xb, wqkvb, wob);

  // Q,K projection: C[s][(q|k) dims], N=2048
  gemm_nt<1><<<dim3(512), dim3(256), 0, stream>>>(xb, wqkvb, bq, bk, nullptr,
                                                  nullptr, QKVb, M, 2048, DM);

  // V^T projection: C[vd][bs] = wv . x^T  -> writes Vt directly (coalesced in s)
  gemm_nt<2><<<dim3(256), dim3(256), 0, stream>>>(wvb, xb, bv, nullptr, nullptr,
                                                  nullptr, Vtb, DM, M, DM);

  attn_kernel<<<dim3(1024), dim3(256), 0, stream>>>(QKVb, QKVb + 4194304, Vtb, Ab);

  gemm_nt<0><<<dim3(256), dim3(256), 0, stream>>>(Ab, wob, bo, nullptr, nullptr,
                                                  (float*)d_out, nullptr, M, DM, DM);
}

// Round 22
// 107.478 us; speedup vs baseline: 1.0542x; 1.0542x over previous
//
#include <hip/hip_runtime.h>
#include <cstdint>
#include <cstddef>

#define S_LEN 2048
#define NH 16
#define HD 64
#define DM 1024
#define WIN 1024

typedef unsigned short u16;
typedef __attribute__((ext_vector_type(8))) short bf16x8;
typedef __attribute__((ext_vector_type(4))) short bf16x4;
typedef __attribute__((ext_vector_type(4))) float f32x4;
typedef __attribute__((ext_vector_type(4))) u16 u16x4;
typedef __attribute__((ext_vector_type(2))) uint32_t u32x2;
typedef __attribute__((ext_vector_type(4))) uint32_t u32x4;

__device__ inline u16 f2b(float f) {
  union { float f; uint32_t u; } x; x.f = f;
  uint32_t r = x.u + 0x7FFFu + ((x.u >> 16) & 1u);
  return (u16)(r >> 16);
}

__device__ inline uint32_t cvt_pk_bf16(float a, float b) {
  uint32_t r;
  asm("v_cvt_pk_bf16_f32 %0, %1, %2" : "=v"(r) : "v"(a), "v"(b));
  return r;
}

__device__ inline void gload16(const void* g, void* l) {
  __builtin_amdgcn_global_load_lds((const __attribute__((address_space(1))) void*)g,
                                   (__attribute__((address_space(3))) void*)l, 16, 0, 0);
}

// ---------------- fused f32 -> bf16 conversion (x + 4 weights, 1 dispatch) --
__global__ __launch_bounds__(256)
void cvt_all(const float* __restrict__ x,
             const float* __restrict__ wq, const float* __restrict__ wk,
             const float* __restrict__ wv, const float* __restrict__ wo,
             u16* __restrict__ xb, u16* __restrict__ wqkvb, u16* __restrict__ wob) {
  size_t i = ((size_t)blockIdx.x * 256 + threadIdx.x) * 4;
  const float* src; u16* dst;
  if (i < 4194304) {                      // x (blocks 0..4095, uniform)
    src = x + i; dst = xb + i;
  } else {
    size_t j = i - 4194304;
    int w = (int)(j >> 20);
    size_t off = j & 1048575;
    switch (w) {
      case 0:  src = wq + off; dst = wqkvb + off; break;
      case 1:  src = wk + off; dst = wqkvb + 1048576 + off; break;
      case 2:  src = wv + off; dst = wqkvb + 2097152 + off; break;
      default: src = wo + off; dst = wob + off; break;
    }
  }
  f32x4 v = *(const f32x4*)src;
  u16x4 o;
  o[0] = f2b(v[0]); o[1] = f2b(v[1]); o[2] = f2b(v[2]); o[3] = f2b(v[3]);
  *(u16x4*)dst = o;
}

// ---------------- bf16 NT GEMM: BK=64, XOR-swizzled LDS, XCD-stripe ---------
// A:[M][K], B:[N][K] bf16 row-major. 128^2 tile, 4 waves x 64x64, BK=64
// (16 K-steps at K=1024 -> half the barriers of BK=32).
// LDS rows are 128B -> 16-way conflict unswizzled; uses the attn-proven
// st-16 XOR swizzle (sw=((o>>7)&7)<<4 on staging source; read chunk^(l15&7)).
// XOR cancels: LDS[row][c^x] == tile[row][c] with x=row&7 (rule #21 both-sides).
template<int EPI>
__global__ __launch_bounds__(256, 4)
void gemm_nt(const u16* __restrict__ A, const u16* __restrict__ B,
             const float* __restrict__ b0, const float* __restrict__ b1,
             const float* __restrict__ b2,
             float* __restrict__ outF, u16* __restrict__ outQ,
             int M, int N, int K) {
  __shared__ u16 As[128 * 64];   // 16KB
  __shared__ u16 Bs[128 * 64];   // 16KB
  const int t = threadIdx.x;
  const int lane = t & 63, wid = t >> 6;
  const int l15 = lane & 15, l4 = lane >> 4;
  const int x = l15 & 7;
  const int wr = wid >> 1, wc = wid & 1;         // 2x2 wave grid, 64x64/wave
  const int bmB = M >> 7, bnB = N >> 7;
  const int stripe = bmB >> 3;
  const int per = stripe * bnB;                  // jobs per XCD
  const int job = (blockIdx.x & 7) * per + (blockIdx.x >> 3);
  const int r_ = job % per;
  const int bm = ((job / per) * stripe + r_ / bnB) << 7;
  const int bn = (r_ % bnB) << 7;
  // staging: o = shot*4096 + t*16 bytes; row = o>>7 = shot*32 + (t>>3);
  // colb = o&127 (shot-invariant); sw = ((row&7)=(t>>3)&7)<<4 (shot-invariant).
  const int srow0 = t >> 3;
  const int colx = ((t * 16) & 127) ^ (((t >> 3) & 7) << 4);
  const char* Ap = (const char*)A + ((size_t)(bm + srow0) * K) * 2 + colx;
  const char* Bp = (const char*)B + ((size_t)(bn + srow0) * K) * 2 + colx;
  const size_t sstr = (size_t)32 * K * 2;        // +32 rows per shot
  char* Asd = (char*)As + t * 16;
  char* Bsd = (char*)Bs + t * 16;
  f32x4 acc[4][4];
#pragma unroll
  for (int i = 0; i < 4; i++)
#pragma unroll
    for (int j = 0; j < 4; j++) acc[i][j] = (f32x4){0.f, 0.f, 0.f, 0.f};

  for (int kb = 0; kb < K; kb += 64) {
    __syncthreads();
#pragma unroll
    for (int shot = 0; shot < 4; shot++) {
      gload16(Ap + (size_t)kb * 2 + shot * sstr, Asd + shot * 4096);
      gload16(Bp + (size_t)kb * 2 + shot * sstr, Bsd + shot * 4096);
    }
    __syncthreads();
#pragma unroll
    for (int ks2 = 0; ks2 < 2; ks2++) {
      bf16x8 af[4], bq[4];
#pragma unroll
      for (int mi = 0; mi < 4; mi++)
        af[mi] = *(bf16x8*)&As[(wr * 64 + mi * 16 + l15) * 64 +
                               (((ks2 * 4 + l4) ^ x) << 3)];
#pragma unroll
      for (int ni = 0; ni < 4; ni++)
        bq[ni] = *(bf16x8*)&Bs[(wc * 64 + ni * 16 + l15) * 64 +
                               (((ks2 * 4 + l4) ^ x) << 3)];
#pragma unroll
      for (int mi = 0; mi < 4; mi++)
#pragma unroll
        for (int ni = 0; ni < 4; ni++)
          acc[mi][ni] = __builtin_amdgcn_mfma_f32_16x16x32_bf16(af[mi], bq[ni], acc[mi][ni], 0, 0, 0);
    }
  }

  const int cb = bn >> 10;
  const float* bp = (EPI == 0) ? b0 : (cb == 0 ? b0 : (cb == 1 ? b1 : b2));
#pragma unroll
  for (int mi = 0; mi < 4; mi++) {
#pragma unroll
    for (int ni = 0; ni < 4; ni++) {
#pragma unroll
      for (int r = 0; r < 4; r++) {
        int row = bm + wr * 64 + mi * 16 + l4 * 4 + r;
        int col = bn + wc * 64 + ni * 16 + l15;
        float v = acc[mi][ni][r] + bp[col & (DM - 1)];
        if (EPI == 0) {
          outF[(size_t)row * N + col] = v;
        } else {
          int b = row >> 11, s = row & (S_LEN - 1);
          int which = col >> 10, cw = col & (DM - 1);
          int h = cw >> 6, d = cw & (HD - 1);
          outQ[(size_t)which * 4194304 +
               (((size_t)(b * NH + h)) * S_LEN + s) * HD + d] = f2b(v);
        }
      }
    }
  }
}

// ---------------- V transpose: [BH][S][64] -> [BH][64][S] (R4-proven) -------
__global__ __launch_bounds__(256)
void transpose_v(const u16* __restrict__ V, u16* __restrict__ Vt) {
  const int bh = blockIdx.y;
  const int s0 = blockIdx.x * 64;
  __shared__ u16 tile[64][72];
  const int t = threadIdx.x;
  const u16* src = V + ((size_t)bh * S_LEN + s0) * HD;
#pragma unroll
  for (int i = 0; i < 2; i++) {
    int e = t * 8 + i * 2048;
    int r = e >> 6, c = e & 63;
    *(bf16x8*)&tile[r][c] = *(const bf16x8*)(src + e);
  }
  __syncthreads();
  u16* dst = Vt + (size_t)bh * HD * S_LEN + s0;
#pragma unroll
  for (int i = 0; i < 2; i++) {
    int e = t * 8 + i * 2048;
    int d = e >> 6, s = e & 63;
    bf16x8 tmp;
#pragma unroll
    for (int j = 0; j < 8; j++) tmp[j] = (short)tile[s + j][d];
    *(bf16x8*)&dst[(size_t)d * S_LEN + s] = tmp;
  }
}

// ---------------- attention: R16-proven (fixed-base softmax, dbuf LDS) ------
__device__ __forceinline__ void stage_tiles(const char* __restrict__ Kg,
                                            const char* __restrict__ Vg,
                                            u16* __restrict__ Kl, u16* __restrict__ Vl,
                                            int t) {
#pragma unroll
  for (int shot = 0; shot < 2; shot++) {
    int o = shot * 4096 + t * 16;
    int sw = ((o >> 7) & 7) << 4;
    gload16(Kg + (o ^ sw), (char*)Kl + o);
    gload16(Vg + (size_t)(o >> 7) * 4096 + ((o & 127) ^ sw), (char*)Vl + o);
  }
}

__device__ __forceinline__ void process_tile16(
    int kb, const u16* __restrict__ Kl, const u16* __restrict__ Vl,
    const bf16x8 qf[2], const float c16[16],
    int qw, int l15, int hi, float slope2, float qks,
    float& lsum, f32x4 O[4]) {
  const int x = l15 & 7;
  f32x4 st[4];
#pragma unroll
  for (int f = 0; f < 4; f++) st[f] = (f32x4){0.f, 0.f, 0.f, 0.f};
#pragma unroll
  for (int ks = 0; ks < 2; ks++)
#pragma unroll
    for (int f = 0; f < 4; f++) {
      bf16x8 kf = *(const bf16x8*)&Kl[(16 * f + l15) * 64 + (((4 * ks + hi) ^ x) << 3)];
      st[f] = __builtin_amdgcn_mfma_f32_16x16x32_bf16(kf, qf[ks], st[f], 0, 0, 0);
    }

  const int dkb = kb + 4 * hi - (qw + l15);
  const float base = slope2 * (float)dkb - 8.f;   // fixed base M0=8 folded in
  const bool interior = (kb + 63 <= qw) && (kb - (qw + 15) > -WIN);
  float p[16];
  if (interior) {
#pragma unroll
    for (int f = 0; f < 4; f++)
#pragma unroll
      for (int r = 0; r < 4; r++)
        p[4 * f + r] = fmaf(st[f][r], qks, base + c16[4 * f + r]);
  } else {
#pragma unroll
    for (int f = 0; f < 4; f++)
#pragma unroll
      for (int r = 0; r < 4; r++) {
        int dk = dkb + 16 * f + r;
        float s = fmaf(st[f][r], qks, base + c16[4 * f + r]);
        p[4 * f + r] = (dk > 0 || dk <= -WIN) ? -3e38f : s;
      }
  }

#pragma unroll
  for (int r = 0; r < 16; r++) p[r] = exp2f(p[r]);
  float a8[8];
#pragma unroll
  for (int r = 0; r < 8; r++) a8[r] = p[r] + p[r + 8];
#pragma unroll
  for (int r = 0; r < 4; r++) a8[r] += a8[r + 4];
  lsum += (a8[0] + a8[1]) + (a8[2] + a8[3]);

  bf16x8 pb[2];
#pragma unroll
  for (int kc = 0; kc < 2; kc++) {
    u32x4 w4;
    w4[0] = cvt_pk_bf16(p[8 * kc + 0], p[8 * kc + 1]);
    w4[1] = cvt_pk_bf16(p[8 * kc + 2], p[8 * kc + 3]);
    w4[2] = cvt_pk_bf16(p[8 * kc + 4], p[8 * kc + 5]);
    w4[3] = cvt_pk_bf16(p[8 * kc + 6], p[8 * kc + 7]);
    pb[kc] = __builtin_bit_cast(bf16x8, w4);
  }

#pragma unroll
  for (int d = 0; d < 4; d++) {
#pragma unroll
    for (int kc = 0; kc < 2; kc++) {
      const int row = (16 * d + l15) * 64;
      bf16x4 a = *(const bf16x4*)&Vl[row + (((4 * kc + (hi >> 1)) ^ x) << 3) + 4 * (hi & 1)];
      bf16x4 bql = *(const bf16x4*)&Vl[row + (((4 * kc + 2 + (hi >> 1)) ^ x) << 3) + 4 * (hi & 1)];
      bf16x8 vf;
      vf[0] = a[0]; vf[1] = a[1]; vf[2] = a[2]; vf[3] = a[3];
      vf[4] = bql[0]; vf[5] = bql[1]; vf[6] = bql[2]; vf[7] = bql[3];
      O[d] = __builtin_amdgcn_mfma_f32_16x16x32_bf16(vf, pb[kc], O[d], 0, 0, 0);
    }
  }
}

__global__ __launch_bounds__(256, 4)
void attn_kernel(const u16* __restrict__ Q, const u16* __restrict__ Kg,
                 const u16* __restrict__ Vt, u16* __restrict__ attn) {
  __shared__ __align__(16) u16 Klds[2][4096];
  __shared__ __align__(16) u16 Vlds[2][4096];
  const int bid = blockIdx.x;
  const int job = (bid & 7) * 128 + (bid >> 3);  // XCD swizzle (1024 % 8 == 0)
  const int bh = job >> 5;
  const int qb = ((31 - (job & 31)) + (bh << 3)) & 31;  // per-CU balance rotation
  const int b = bh >> 4, h = bh & 15;
  const int tid = threadIdx.x;
  const int wid = tid >> 6, lane = tid & 63;
  const int l15 = lane & 15, hi = lane >> 4;
  const int q0 = qb << 6;
  const int qw = q0 + 16 * wid;
  const u16* Qp = Q + (size_t)bh * (S_LEN * HD);
  const char* Kbase = (const char*)(Kg + (size_t)bh * (S_LEN * HD));
  const char* Vbase = (const char*)(Vt + (size_t)bh * (HD * S_LEN));

  bf16x8 qf[2];
#pragma unroll
  for (int ks = 0; ks < 2; ks++)
    qf[ks] = *(const bf16x8*)(Qp + (size_t)(qw + l15) * HD + 32 * ks + 8 * hi);

  const float slope2 = exp2f(-0.5f * (float)(h + 1)) * 1.44269504f;
  const float qks = 0.125f * 1.44269504f;
  float c16[16];
#pragma unroll
  for (int f = 0; f < 4; f++)
#pragma unroll
    for (int r = 0; r < 4; r++) c16[4 * f + r] = slope2 * (float)(16 * f + r);

  float lsum = 0.f;
  f32x4 O[4];
#pragma unroll
  for (int d = 0; d < 4; d++) O[d] = (f32x4){0.f, 0.f, 0.f, 0.f};

  int lo_u = q0 - (WIN - 1); if (lo_u < 0) lo_u = 0; lo_u &= ~63;
  const int hi_u = q0;
  int lo_w = qw - (WIN - 1); if (lo_w < 0) lo_w = 0; lo_w &= ~63;
  const int last_w = (qw + 15) & ~63;

  stage_tiles(Kbase + (size_t)lo_u * 128, Vbase + (size_t)lo_u * 2,
              Klds[0], Vlds[0], tid);
  int cur = 0;
  for (int kb = lo_u; kb <= hi_u; kb += 64) {
    __syncthreads();   // tile kb resident; prior reads of buf[cur^1] done
    if (kb + 64 <= hi_u)
      stage_tiles(Kbase + (size_t)(kb + 64) * 128, Vbase + (size_t)(kb + 64) * 2,
                  Klds[cur ^ 1], Vlds[cur ^ 1], tid);
    if (kb >= lo_w && kb <= last_w)    // wave-uniform branch
      process_tile16(kb, Klds[cur], Vlds[cur], qf, c16,
                     qw, l15, hi, slope2, qks, lsum, O);
    cur ^= 1;
  }

  // deferred cross-lane lsum reduce (row = lanes {l15, l15+16, l15+32, l15+48})
  lsum += __shfl_xor(lsum, 16, 64);
  lsum += __shfl_xor(lsum, 32, 64);

  const float invl = 1.f / lsum;
  u16* op = attn + ((size_t)(b * S_LEN) + qw + l15) * DM + h * HD + 4 * hi;
#pragma unroll
  for (int d = 0; d < 4; d++) {
    u32x2 w;
    w[0] = cvt_pk_bf16(O[d][0] * invl, O[d][1] * invl);
    w[1] = cvt_pk_bf16(O[d][2] * invl, O[d][3] * invl);
    *(u32x2*)(op + d * 16) = w;
  }
}

// ---------------- launch ----------------
extern "C" void kernel_launch(void* const* d_in, const int* in_sizes, int n_in,
                              void* d_out, int out_size, void* d_ws, size_t ws_size,
                              hipStream_t stream) {
  const float* x  = (const float*)d_in[0];
  const float* wq = (const float*)d_in[1];
  const float* bq = (const float*)d_in[2];
  const float* wk = (const float*)d_in[3];
  const float* bk = (const float*)d_in[4];
  const float* wv = (const float*)d_in[5];
  const float* bv = (const float*)d_in[6];
  const float* wo = (const float*)d_in[7];
  const float* bo = (const float*)d_in[8];

  char* ws = (char*)d_ws;
  u16* xb    = (u16*)(ws);                  // 8 MB  [4096][1024]
  u16* wqkvb = (u16*)(ws + 8388608);        // 6 MB  [3072][1024]
  u16* wob   = (u16*)(ws + 14680064);       // 2 MB  [1024][1024]
  u16* QKVb  = (u16*)(ws + 16777216);       // 24 MB: Q|K|V row layout [bh][s][64]
  u16* Vtb   = (u16*)(ws + 41943040);       // 8 MB  [BH][64][S]
  u16* Ab    = (u16*)(ws + 50331648);       // 8 MB  [B*S][1024]
  u16* Vb    = QKVb + 2 * 4194304;

  const int M = 4096;

  cvt_all<<<dim3(8192), dim3(256), 0, stream>>>(x, wq, wk, wv, wo,
                                                xb, wqkvb, wob);

  gemm_nt<1><<<dim3(768), dim3(256), 0, stream>>>(xb, wqkvb, bq, bk, bv,
                                                  nullptr, QKVb, M, 3072, DM);

  transpose_v<<<dim3(32, 32), dim3(256), 0, stream>>>(Vb, Vtb);

  attn_kernel<<<dim3(1024), dim3(256), 0, stream>>>(QKVb, QKVb + 4194304, Vtb, Ab);

  gemm_nt<0><<<dim3(256), dim3(256), 0, stream>>>(Ab, wob, bo, nullptr, nullptr,
                                                  (float*)d_out, nullptr, M, DM, DM);
}

// Round 23
// 104.291 us; speedup vs baseline: 1.0864x; 1.0306x over previous
//
#include <hip/hip_runtime.h>
#include <cstdint>
#include <cstddef>

#define S_LEN 2048
#define NH 16
#define HD 64
#define DM 1024
#define WIN 1024

typedef unsigned short u16;
typedef __attribute__((ext_vector_type(8))) short bf16x8;
typedef __attribute__((ext_vector_type(4))) short bf16x4;
typedef __attribute__((ext_vector_type(4))) float f32x4;
typedef __attribute__((ext_vector_type(4))) u16 u16x4;
typedef __attribute__((ext_vector_type(2))) uint32_t u32x2;
typedef __attribute__((ext_vector_type(4))) uint32_t u32x4;

__device__ inline u16 f2b(float f) {
  union { float f; uint32_t u; } x; x.f = f;
  uint32_t r = x.u + 0x7FFFu + ((x.u >> 16) & 1u);
  return (u16)(r >> 16);
}

__device__ inline uint32_t cvt_pk_bf16(float a, float b) {
  uint32_t r;
  asm("v_cvt_pk_bf16_f32 %0, %1, %2" : "=v"(r) : "v"(a), "v"(b));
  return r;
}

__device__ inline void gload16(const void* g, void* l) {
  __builtin_amdgcn_global_load_lds((const __attribute__((address_space(1))) void*)g,
                                   (__attribute__((address_space(3))) void*)l, 16, 0, 0);
}

// ---------------- fused f32 -> bf16 conversion (x + 4 weights, 1 dispatch) --
__global__ __launch_bounds__(256)
void cvt_all(const float* __restrict__ x,
             const float* __restrict__ wq, const float* __restrict__ wk,
             const float* __restrict__ wv, const float* __restrict__ wo,
             u16* __restrict__ xb, u16* __restrict__ wqkvb, u16* __restrict__ wob) {
  size_t i = ((size_t)blockIdx.x * 256 + threadIdx.x) * 4;
  const float* src; u16* dst;
  if (i < 4194304) {                      // x (blocks 0..4095, uniform)
    src = x + i; dst = xb + i;
  } else {
    size_t j = i - 4194304;
    int w = (int)(j >> 20);
    size_t off = j & 1048575;
    switch (w) {
      case 0:  src = wq + off; dst = wqkvb + off; break;
      case 1:  src = wk + off; dst = wqkvb + 1048576 + off; break;
      case 2:  src = wv + off; dst = wqkvb + 2097152 + off; break;
      default: src = wo + off; dst = wob + off; break;
    }
  }
  f32x4 v = *(const f32x4*)src;
  u16x4 o;
  o[0] = f2b(v[0]); o[1] = f2b(v[1]); o[2] = f2b(v[2]); o[3] = f2b(v[3]);
  *(u16x4*)dst = o;
}

// ---------------- bf16 NT GEMM: BK=64, XOR-swizzled LDS, XCD-stripe ---------
// A:[M][K], B:[N][K] bf16 row-major. 128xBN tile, BK=64.
// BN=128: 4 waves in 2x2, wave tile 64x64 (R20/R22-proven).
// BN=64:  4 waves stacked in M, wave tile 32x64 -> 2x the blocks for small-N
//         dispatches (out-proj was 1 block/CU; this makes it 2).
// EPI 0: f32 -> outF[row*N+col], bias b0[col]
// EPI 1: fused QKV epilogue (proven mapping), bias by col>>10
template<int EPI, int BN>
__global__ __launch_bounds__(256, 4)
void gemm_nt(const u16* __restrict__ A, const u16* __restrict__ B,
             const float* __restrict__ b0, const float* __restrict__ b1,
             const float* __restrict__ b2,
             float* __restrict__ outF, u16* __restrict__ outQ,
             int M, int N, int K) {
  constexpr int MI = (BN == 128) ? 4 : 2;        // per-wave 16-row tiles
  __shared__ u16 As[128 * 64];                   // 16KB
  __shared__ u16 Bs[BN * 64];                    // 16KB or 8KB
  const int t = threadIdx.x;
  const int lane = t & 63, wid = t >> 6;
  const int l15 = lane & 15, l4 = lane >> 4;
  const int x = l15 & 7;
  const int wr = (BN == 128) ? (wid >> 1) : wid;
  const int wc = (BN == 128) ? (wid & 1) : 0;
  const int bmB = M >> 7, bnB = N / BN;
  const int stripe = bmB >> 3;
  const int per = stripe * bnB;                  // jobs per XCD
  const int job = (blockIdx.x & 7) * per + (blockIdx.x >> 3);
  const int r_ = job % per;
  const int bm = ((job / per) * stripe + r_ / bnB) << 7;
  const int bn = (r_ % bnB) * BN;
  const int srow0 = t >> 3;
  const int colx = ((t * 16) & 127) ^ (((t >> 3) & 7) << 4);
  const char* Ap = (const char*)A + ((size_t)(bm + srow0) * K) * 2 + colx;
  const char* Bp = (const char*)B + ((size_t)(bn + srow0) * K) * 2 + colx;
  const size_t sstr = (size_t)32 * K * 2;        // +32 rows per shot
  char* Asd = (char*)As + t * 16;
  char* Bsd = (char*)Bs + t * 16;
  f32x4 acc[MI][4];
#pragma unroll
  for (int i = 0; i < MI; i++)
#pragma unroll
    for (int j = 0; j < 4; j++) acc[i][j] = (f32x4){0.f, 0.f, 0.f, 0.f};

  for (int kb = 0; kb < K; kb += 64) {
    __syncthreads();
#pragma unroll
    for (int shot = 0; shot < 4; shot++)
      gload16(Ap + (size_t)kb * 2 + shot * sstr, Asd + shot * 4096);
#pragma unroll
    for (int shot = 0; shot < BN / 32; shot++)
      gload16(Bp + (size_t)kb * 2 + shot * sstr, Bsd + shot * 4096);
    __syncthreads();
#pragma unroll
    for (int ks2 = 0; ks2 < 2; ks2++) {
      bf16x8 af[MI], bq[4];
#pragma unroll
      for (int mi = 0; mi < MI; mi++)
        af[mi] = *(bf16x8*)&As[(wr * (16 * MI) + mi * 16 + l15) * 64 +
                               (((ks2 * 4 + l4) ^ x) << 3)];
#pragma unroll
      for (int ni = 0; ni < 4; ni++)
        bq[ni] = *(bf16x8*)&Bs[(wc * 64 + ni * 16 + l15) * 64 +
                               (((ks2 * 4 + l4) ^ x) << 3)];
#pragma unroll
      for (int mi = 0; mi < MI; mi++)
#pragma unroll
        for (int ni = 0; ni < 4; ni++)
          acc[mi][ni] = __builtin_amdgcn_mfma_f32_16x16x32_bf16(af[mi], bq[ni], acc[mi][ni], 0, 0, 0);
    }
  }

  const int cb = bn >> 10;
  const float* bp = (EPI == 0) ? b0 : (cb == 0 ? b0 : (cb == 1 ? b1 : b2));
#pragma unroll
  for (int mi = 0; mi < MI; mi++) {
#pragma unroll
    for (int ni = 0; ni < 4; ni++) {
#pragma unroll
      for (int r = 0; r < 4; r++) {
        int row = bm + wr * (16 * MI) + mi * 16 + l4 * 4 + r;
        int col = bn + wc * 64 + ni * 16 + l15;
        float v = acc[mi][ni][r] + bp[col & (DM - 1)];
        if (EPI == 0) {
          outF[(size_t)row * N + col] = v;
        } else {
          int b = row >> 11, s = row & (S_LEN - 1);
          int which = col >> 10, cw = col & (DM - 1);
          int h = cw >> 6, d = cw & (HD - 1);
          outQ[(size_t)which * 4194304 +
               (((size_t)(b * NH + h)) * S_LEN + s) * HD + d] = f2b(v);
        }
      }
    }
  }
}

// ---------------- V transpose: [BH][S][64] -> [BH][64][S] (R4-proven) -------
__global__ __launch_bounds__(256)
void transpose_v(const u16* __restrict__ V, u16* __restrict__ Vt) {
  const int bh = blockIdx.y;
  const int s0 = blockIdx.x * 64;
  __shared__ u16 tile[64][72];
  const int t = threadIdx.x;
  const u16* src = V + ((size_t)bh * S_LEN + s0) * HD;
#pragma unroll
  for (int i = 0; i < 2; i++) {
    int e = t * 8 + i * 2048;
    int r = e >> 6, c = e & 63;
    *(bf16x8*)&tile[r][c] = *(const bf16x8*)(src + e);
  }
  __syncthreads();
  u16* dst = Vt + (size_t)bh * HD * S_LEN + s0;
#pragma unroll
  for (int i = 0; i < 2; i++) {
    int e = t * 8 + i * 2048;
    int d = e >> 6, s = e & 63;
    bf16x8 tmp;
#pragma unroll
    for (int j = 0; j < 8; j++) tmp[j] = (short)tile[s + j][d];
    *(bf16x8*)&dst[(size_t)d * S_LEN + s] = tmp;
  }
}

// ---------------- attention: R16-proven (fixed-base softmax, dbuf LDS) ------
__device__ __forceinline__ void stage_tiles(const char* __restrict__ Kg,
                                            const char* __restrict__ Vg,
                                            u16* __restrict__ Kl, u16* __restrict__ Vl,
                                            int t) {
#pragma unroll
  for (int shot = 0; shot < 2; shot++) {
    int o = shot * 4096 + t * 16;
    int sw = ((o >> 7) & 7) << 4;
    gload16(Kg + (o ^ sw), (char*)Kl + o);
    gload16(Vg + (size_t)(o >> 7) * 4096 + ((o & 127) ^ sw), (char*)Vl + o);
  }
}

__device__ __forceinline__ void process_tile16(
    int kb, const u16* __restrict__ Kl, const u16* __restrict__ Vl,
    const bf16x8 qf[2], const float c16[16],
    int qw, int l15, int hi, float slope2, float qks,
    float& lsum, f32x4 O[4]) {
  const int x = l15 & 7;
  f32x4 st[4];
#pragma unroll
  for (int f = 0; f < 4; f++) st[f] = (f32x4){0.f, 0.f, 0.f, 0.f};
#pragma unroll
  for (int ks = 0; ks < 2; ks++)
#pragma unroll
    for (int f = 0; f < 4; f++) {
      bf16x8 kf = *(const bf16x8*)&Kl[(16 * f + l15) * 64 + (((4 * ks + hi) ^ x) << 3)];
      st[f] = __builtin_amdgcn_mfma_f32_16x16x32_bf16(kf, qf[ks], st[f], 0, 0, 0);
    }

  const int dkb = kb + 4 * hi - (qw + l15);
  const float base = slope2 * (float)dkb - 8.f;   // fixed base M0=8 folded in
  const bool interior = (kb + 63 <= qw) && (kb - (qw + 15) > -WIN);
  float p[16];
  if (interior) {
#pragma unroll
    for (int f = 0; f < 4; f++)
#pragma unroll
      for (int r = 0; r < 4; r++)
        p[4 * f + r] = fmaf(st[f][r], qks, base + c16[4 * f + r]);
  } else {
#pragma unroll
    for (int f = 0; f < 4; f++)
#pragma unroll
      for (int r = 0; r < 4; r++) {
        int dk = dkb + 16 * f + r;
        float s = fmaf(st[f][r], qks, base + c16[4 * f + r]);
        p[4 * f + r] = (dk > 0 || dk <= -WIN) ? -3e38f : s;
      }
  }

#pragma unroll
  for (int r = 0; r < 16; r++) p[r] = exp2f(p[r]);
  float a8[8];
#pragma unroll
  for (int r = 0; r < 8; r++) a8[r] = p[r] + p[r + 8];
#pragma unroll
  for (int r = 0; r < 4; r++) a8[r] += a8[r + 4];
  lsum += (a8[0] + a8[1]) + (a8[2] + a8[3]);

  bf16x8 pb[2];
#pragma unroll
  for (int kc = 0; kc < 2; kc++) {
    u32x4 w4;
    w4[0] = cvt_pk_bf16(p[8 * kc + 0], p[8 * kc + 1]);
    w4[1] = cvt_pk_bf16(p[8 * kc + 2], p[8 * kc + 3]);
    w4[2] = cvt_pk_bf16(p[8 * kc + 4], p[8 * kc + 5]);
    w4[3] = cvt_pk_bf16(p[8 * kc + 6], p[8 * kc + 7]);
    pb[kc] = __builtin_bit_cast(bf16x8, w4);
  }

#pragma unroll
  for (int d = 0; d < 4; d++) {
#pragma unroll
    for (int kc = 0; kc < 2; kc++) {
      const int row = (16 * d + l15) * 64;
      bf16x4 a = *(const bf16x4*)&Vl[row + (((4 * kc + (hi >> 1)) ^ x) << 3) + 4 * (hi & 1)];
      bf16x4 bql = *(const bf16x4*)&Vl[row + (((4 * kc + 2 + (hi >> 1)) ^ x) << 3) + 4 * (hi & 1)];
      bf16x8 vf;
      vf[0] = a[0]; vf[1] = a[1]; vf[2] = a[2]; vf[3] = a[3];
      vf[4] = bql[0]; vf[5] = bql[1]; vf[6] = bql[2]; vf[7] = bql[3];
      O[d] = __builtin_amdgcn_mfma_f32_16x16x32_bf16(vf, pb[kc], O[d], 0, 0, 0);
    }
  }
}

__global__ __launch_bounds__(256, 4)
void attn_kernel(const u16* __restrict__ Q, const u16* __restrict__ Kg,
                 const u16* __restrict__ Vt, u16* __restrict__ attn) {
  __shared__ __align__(16) u16 Klds[2][4096];
  __shared__ __align__(16) u16 Vlds[2][4096];
  const int bid = blockIdx.x;
  const int job = (bid & 7) * 128 + (bid >> 3);  // XCD swizzle (1024 % 8 == 0)
  const int bh = job >> 5;
  const int qb = ((31 - (job & 31)) + (bh << 3)) & 31;  // per-CU balance rotation
  const int b = bh >> 4, h = bh & 15;
  const int tid = threadIdx.x;
  const int wid = tid >> 6, lane = tid & 63;
  const int l15 = lane & 15, hi = lane >> 4;
  const int q0 = qb << 6;
  const int qw = q0 + 16 * wid;
  const u16* Qp = Q + (size_t)bh * (S_LEN * HD);
  const char* Kbase = (const char*)(Kg + (size_t)bh * (S_LEN * HD));
  const char* Vbase = (const char*)(Vt + (size_t)bh * (HD * S_LEN));

  bf16x8 qf[2];
#pragma unroll
  for (int ks = 0; ks < 2; ks++)
    qf[ks] = *(const bf16x8*)(Qp + (size_t)(qw + l15) * HD + 32 * ks + 8 * hi);

  const float slope2 = exp2f(-0.5f * (float)(h + 1)) * 1.44269504f;
  const float qks = 0.125f * 1.44269504f;
  float c16[16];
#pragma unroll
  for (int f = 0; f < 4; f++)
#pragma unroll
    for (int r = 0; r < 4; r++) c16[4 * f + r] = slope2 * (float)(16 * f + r);

  float lsum = 0.f;
  f32x4 O[4];
#pragma unroll
  for (int d = 0; d < 4; d++) O[d] = (f32x4){0.f, 0.f, 0.f, 0.f};

  int lo_u = q0 - (WIN - 1); if (lo_u < 0) lo_u = 0; lo_u &= ~63;
  const int hi_u = q0;
  int lo_w = qw - (WIN - 1); if (lo_w < 0) lo_w = 0; lo_w &= ~63;
  const int last_w = (qw + 15) & ~63;

  stage_tiles(Kbase + (size_t)lo_u * 128, Vbase + (size_t)lo_u * 2,
              Klds[0], Vlds[0], tid);
  int cur = 0;
  for (int kb = lo_u; kb <= hi_u; kb += 64) {
    __syncthreads();   // tile kb resident; prior reads of buf[cur^1] done
    if (kb + 64 <= hi_u)
      stage_tiles(Kbase + (size_t)(kb + 64) * 128, Vbase + (size_t)(kb + 64) * 2,
                  Klds[cur ^ 1], Vlds[cur ^ 1], tid);
    if (kb >= lo_w && kb <= last_w)    // wave-uniform branch
      process_tile16(kb, Klds[cur], Vlds[cur], qf, c16,
                     qw, l15, hi, slope2, qks, lsum, O);
    cur ^= 1;
  }

  // deferred cross-lane lsum reduce (row = lanes {l15, l15+16, l15+32, l15+48})
  lsum += __shfl_xor(lsum, 16, 64);
  lsum += __shfl_xor(lsum, 32, 64);

  const float invl = 1.f / lsum;
  u16* op = attn + ((size_t)(b * S_LEN) + qw + l15) * DM + h * HD + 4 * hi;
#pragma unroll
  for (int d = 0; d < 4; d++) {
    u32x2 w;
    w[0] = cvt_pk_bf16(O[d][0] * invl, O[d][1] * invl);
    w[1] = cvt_pk_bf16(O[d][2] * invl, O[d][3] * invl);
    *(u32x2*)(op + d * 16) = w;
  }
}

// ---------------- launch ----------------
extern "C" void kernel_launch(void* const* d_in, const int* in_sizes, int n_in,
                              void* d_out, int out_size, void* d_ws, size_t ws_size,
                              hipStream_t stream) {
  const float* x  = (const float*)d_in[0];
  const float* wq = (const float*)d_in[1];
  const float* bq = (const float*)d_in[2];
  const float* wk = (const float*)d_in[3];
  const float* bk = (const float*)d_in[4];
  const float* wv = (const float*)d_in[5];
  const float* bv = (const float*)d_in[6];
  const float* wo = (const float*)d_in[7];
  const float* bo = (const float*)d_in[8];

  char* ws = (char*)d_ws;
  u16* xb    = (u16*)(ws);                  // 8 MB  [4096][1024]
  u16* wqkvb = (u16*)(ws + 8388608);        // 6 MB  [3072][1024]
  u16* wob   = (u16*)(ws + 14680064);       // 2 MB  [1024][1024]
  u16* QKVb  = (u16*)(ws + 16777216);       // 24 MB: Q|K|V row layout [bh][s][64]
  u16* Vtb   = (u16*)(ws + 41943040);       // 8 MB  [BH][64][S]
  u16* Ab    = (u16*)(ws + 50331648);       // 8 MB  [B*S][1024]
  u16* Vb    = QKVb + 2 * 4194304;

  const int M = 4096;

  cvt_all<<<dim3(8192), dim3(256), 0, stream>>>(x, wq, wk, wv, wo,
                                                xb, wqkvb, wob);

  gemm_nt<1, 128><<<dim3(768), dim3(256), 0, stream>>>(xb, wqkvb, bq, bk, bv,
                                                       nullptr, QKVb, M, 3072, DM);

  transpose_v<<<dim3(32, 32), dim3(256), 0, stream>>>(Vb, Vtb);

  attn_kernel<<<dim3(1024), dim3(256), 0, stream>>>(QKVb, QKVb + 4194304, Vtb, Ab);

  // out-proj: BN=64 -> 512 blocks = 2 blocks/CU (was 256 = 1/CU, latency-exposed)
  gemm_nt<0, 64><<<dim3(512), dim3(256), 0, stream>>>(Ab, wob, bo, nullptr, nullptr,
                                                      (float*)d_out, nullptr, M, DM, DM);
}